// Round 1
// baseline (581.517 us; speedup 1.0000x reference)
//
#include <hip/hip_runtime.h>

#define DSZ 96
#define CIN 16
#define NF  16

// One thread per voxel. Dense compute (sparsity is per-lane random -> no wave-level
// skip possible), masked write. w/bias read via uniform indices -> scalar loads.
__global__ __launch_bounds__(256) void sparse_conv_f32(
    const float* __restrict__ feat, const int* __restrict__ index,
    const float* __restrict__ w, const float* __restrict__ bias,
    float* __restrict__ out) {
  const int v = blockIdx.x * 256 + threadIdx.x;
  const int z = v % DSZ;
  int t = v / DSZ;
  const int y = t % DSZ;
  t /= DSZ;
  const int x = t % DSZ;
  const int bb = t / DSZ;

  float acc[NF];
#pragma unroll
  for (int f = 0; f < NF; ++f) acc[f] = bias[f];

  const bool active = (index[v] != 0);

#pragma unroll 1
  for (int kx = -1; kx <= 1; ++kx) {
    const int xx = x + kx;
    const bool okx = ((unsigned)xx < (unsigned)DSZ);
#pragma unroll 1
    for (int ky = -1; ky <= 1; ++ky) {
      const int yy = y + ky;
      const bool oky = okx && ((unsigned)yy < (unsigned)DSZ);
#pragma unroll 1
      for (int kz = -1; kz <= 1; ++kz) {
        const int zz = z + kz;
        const bool ok = oky && ((unsigned)zz < (unsigned)DSZ);
        const long long off =
            ((((long long)bb * DSZ + xx) * DSZ + yy) * DSZ + zz) * CIN;
        float4 q0, q1, q2, q3;
        if (ok) {
          const float4* fp = reinterpret_cast<const float4*>(feat + off);
          q0 = fp[0];
          q1 = fp[1];
          q2 = fp[2];
          q3 = fp[3];
        } else {
          q0 = q1 = q2 = q3 = make_float4(0.f, 0.f, 0.f, 0.f);
        }
        const float fv[CIN] = {q0.x, q0.y, q0.z, q0.w, q1.x, q1.y, q1.z, q1.w,
                               q2.x, q2.y, q2.z, q2.w, q3.x, q3.y, q3.z, q3.w};
        // w row = ((dx*3+dy)*3+dz)*CIN + ci (dx = kx+1 etc.), col = f
        const float* wr = w + ((((kx + 1) * 3 + (ky + 1)) * 3 + (kz + 1)) * CIN) * NF;
#pragma unroll
        for (int ci = 0; ci < CIN; ++ci) {
          const float fvv = fv[ci];
#pragma unroll
          for (int f = 0; f < NF; ++f)
            acc[f] = fmaf(fvv, wr[ci * NF + f], acc[f]);
        }
      }
    }
  }

  float4* op = reinterpret_cast<float4*>(out + (long long)v * NF);
  if (active) {
    op[0] = make_float4(acc[0], acc[1], acc[2], acc[3]);
    op[1] = make_float4(acc[4], acc[5], acc[6], acc[7]);
    op[2] = make_float4(acc[8], acc[9], acc[10], acc[11]);
    op[3] = make_float4(acc[12], acc[13], acc[14], acc[15]);
  } else {
    const float4 z4 = make_float4(0.f, 0.f, 0.f, 0.f);
    op[0] = z4;
    op[1] = z4;
    op[2] = z4;
    op[3] = z4;
  }
}

extern "C" void kernel_launch(void* const* d_in, const int* in_sizes, int n_in,
                              void* d_out, int out_size, void* d_ws, size_t ws_size,
                              hipStream_t stream) {
  const float* feat  = (const float*)d_in[0];
  const int*   index = (const int*)d_in[1];
  const float* w     = (const float*)d_in[2];
  const float* bias  = (const float*)d_in[3];
  float*       out   = (float*)d_out;

  const int nvox = in_sizes[1];       // 4*96*96*96 = 3,538,944
  const int blocks = nvox / 256;      // exact: 13824
  sparse_conv_f32<<<blocks, 256, 0, stream>>>(feat, index, w, bias, out);
}

// Round 2
// 458.615 us; speedup vs baseline: 1.2680x; 1.2680x over previous
//
#include <hip/hip_runtime.h>
#include <hip/hip_bf16.h>

#define DSZ 96
#define CIN 16
#define NF  16

typedef __attribute__((ext_vector_type(8))) short short8;   // 8 bf16 in 4 VGPRs
typedef __attribute__((ext_vector_type(4))) float f32x4;    // MFMA C/D

// ---------------- prepass: pack w into B-fragment layout ----------------
// Logical k within a K=32 MFMA step: k = (laneHi=l>>4)*8 + j.
// tap_local = k>>4 = l>>5 ; ci = k&15 = ((l>>4)&1)*8 + j.
// Fragment t covers taps {2t, 2t+1}; tap 27 is zero padding.
__global__ void pack_w(const float* __restrict__ w, short* __restrict__ wpack) {
  const int t = threadIdx.x >> 6;   // 0..13
  const int l = threadIdx.x & 63;
  const int tap = 2 * t + (l >> 5);
  const int cib = ((l >> 4) & 1) * 8;
  const int f = l & 15;
  short v[8];
#pragma unroll
  for (int j = 0; j < 8; ++j) {
    float x = (tap <= 26) ? w[(tap * 16 + cib + j) * 16 + f] : 0.0f;
    unsigned u = __float_as_uint(x);
    u = (u + 0x7FFFu + ((u >> 16) & 1u)) >> 16;  // RNE to bf16
    v[j] = (short)u;
  }
  short8* dst = reinterpret_cast<short8*>(wpack) + (t * 64 + l);
  short8 s;
#pragma unroll
  for (int j = 0; j < 8; ++j) s[j] = v[j];
  *dst = s;
}

// ---------------- main: MFMA conv ----------------
// One wave per (b,x,y, z-tile of 16). M=16 z, N=16 filters, K=32 (2 taps)/MFMA.
__global__ __launch_bounds__(256) void conv_mfma(
    const float* __restrict__ feat, const int* __restrict__ index,
    const float* __restrict__ bias, const short8* __restrict__ wpack,
    float* __restrict__ out) {
  const int lane = threadIdx.x & 63;
  const int wid = threadIdx.x >> 6;
  int T = blockIdx.x * 4 + wid;
  const int zt = T % 6;  T /= 6;
  const int y  = T % DSZ; T /= DSZ;
  const int x  = T % DSZ;
  const int b  = T / DSZ;
  const int z0 = zt * 16;

  // B fragments (w) — resident in registers
  short8 bw[14];
#pragma unroll
  for (int t = 0; t < 14; ++t) bw[t] = wpack[t * 64 + lane];

  const int row = lane & 15;          // A-fragment row = z within tile
  const int cib = ((lane >> 4) & 1) * 8;
  const int h5  = lane >> 5;          // which tap of the pair
  const int zrow = z0 + row;

  // 9 xy line bases + validity (indices compile-time in the unrolled loop)
  int  lb[9];
  bool okxy[9];
#pragma unroll
  for (int d = 0; d < 9; ++d) {
    const int dx = d / 3, dy = d % 3;
    const int xx = x + dx - 1, yy = y + dy - 1;
    okxy[d] = ((unsigned)xx < (unsigned)DSZ) & ((unsigned)yy < (unsigned)DSZ);
    lb[d] = ((b * DSZ + xx) * DSZ + yy) * DSZ;  // used only when okxy
  }

  f32x4 acc = {0.f, 0.f, 0.f, 0.f};

#pragma unroll
  for (int t = 0; t < 14; ++t) {
    const int tapA = 2 * t, tapB = 2 * t + 1;
    const int dxa = tapA / 9, dya = (tapA / 3) % 3, dza = tapA % 3;
    const int dxb = tapB / 9, dyb = (tapB / 3) % 3, dzb = tapB % 3;

    int zz, lbase;
    bool okc;
    if (tapB <= 26) {
      zz    = zrow + (h5 ? dzb : dza) - 1;
      lbase = h5 ? lb[dxb * 3 + dyb] : lb[dxa * 3 + dya];
      okc   = (h5 ? okxy[dxb * 3 + dyb] : okxy[dxa * 3 + dya]) &&
              ((unsigned)zz < (unsigned)DSZ);
    } else {  // t==13: second tap is the zero pad
      zz    = zrow + dza - 1;
      lbase = lb[dxa * 3 + dya];
      okc   = (h5 == 0) && okxy[dxa * 3 + dya] && ((unsigned)zz < (unsigned)DSZ);
    }

    int eoff = (lbase + zz) * CIN + cib;  // f32 element offset
    eoff = okc ? eoff : 0;                 // clamp OOB to a safe address
    const float4* p = reinterpret_cast<const float4*>(feat + eoff);
    const float4 q0 = p[0];
    const float4 q1 = p[1];

    // truncate-pack 8 f32 -> 8 bf16 (4 u32 words)
    unsigned w0 = (__float_as_uint(q0.y) & 0xFFFF0000u) | (__float_as_uint(q0.x) >> 16);
    unsigned w1 = (__float_as_uint(q0.w) & 0xFFFF0000u) | (__float_as_uint(q0.z) >> 16);
    unsigned w2 = (__float_as_uint(q1.y) & 0xFFFF0000u) | (__float_as_uint(q1.x) >> 16);
    unsigned w3 = (__float_as_uint(q1.w) & 0xFFFF0000u) | (__float_as_uint(q1.z) >> 16);
    if (!okc) { w0 = 0u; w1 = 0u; w2 = 0u; w3 = 0u; }

    union { unsigned u[4]; short8 s; } cv;
    cv.u[0] = w0; cv.u[1] = w1; cv.u[2] = w2; cv.u[3] = w3;

    acc = __builtin_amdgcn_mfma_f32_16x16x32_bf16(cv.s, bw[t], acc, 0, 0, 0);
  }

  // epilogue: +bias, mask by index, store f32
  const int f = lane & 15;
  const int h = lane >> 4;
  const float bf = bias[f];
  const int vbase = ((b * DSZ + x) * DSZ + y) * DSZ + z0;
#pragma unroll
  for (int r = 0; r < 4; ++r) {
    const int g = vbase + h * 4 + r;          // C/D row = (lane>>4)*4 + r
    const bool act = (index[g] != 0);
    out[(long long)g * NF + f] = act ? (acc[r] + bf) : 0.0f;
  }
}

// ---------------- fallback (tiny ws): round-1 f32 kernel ----------------
__global__ __launch_bounds__(256) void sparse_conv_f32(
    const float* __restrict__ feat, const int* __restrict__ index,
    const float* __restrict__ w, const float* __restrict__ bias,
    float* __restrict__ out) {
  const int v = blockIdx.x * 256 + threadIdx.x;
  const int z = v % DSZ;
  int t = v / DSZ;
  const int y = t % DSZ; t /= DSZ;
  const int x = t % DSZ;
  const int bb = t / DSZ;
  float acc[NF];
#pragma unroll
  for (int f = 0; f < NF; ++f) acc[f] = bias[f];
  const bool active = (index[v] != 0);
#pragma unroll 1
  for (int kx = -1; kx <= 1; ++kx) {
    const int xx = x + kx;
    const bool okx = ((unsigned)xx < (unsigned)DSZ);
#pragma unroll 1
    for (int ky = -1; ky <= 1; ++ky) {
      const int yy = y + ky;
      const bool oky = okx && ((unsigned)yy < (unsigned)DSZ);
#pragma unroll 1
      for (int kz = -1; kz <= 1; ++kz) {
        const int zz = z + kz;
        const bool ok = oky && ((unsigned)zz < (unsigned)DSZ);
        const long long off = ((((long long)bb * DSZ + xx) * DSZ + yy) * DSZ + zz) * CIN;
        float4 q0, q1, q2, q3;
        if (ok) {
          const float4* fp = reinterpret_cast<const float4*>(feat + off);
          q0 = fp[0]; q1 = fp[1]; q2 = fp[2]; q3 = fp[3];
        } else {
          q0 = q1 = q2 = q3 = make_float4(0.f, 0.f, 0.f, 0.f);
        }
        const float fv[CIN] = {q0.x, q0.y, q0.z, q0.w, q1.x, q1.y, q1.z, q1.w,
                               q2.x, q2.y, q2.z, q2.w, q3.x, q3.y, q3.z, q3.w};
        const float* wr = w + ((((kx + 1) * 3 + (ky + 1)) * 3 + (kz + 1)) * CIN) * NF;
#pragma unroll
        for (int ci = 0; ci < CIN; ++ci) {
          const float fvv = fv[ci];
#pragma unroll
          for (int f = 0; f < NF; ++f) acc[f] = fmaf(fvv, wr[ci * NF + f], acc[f]);
        }
      }
    }
  }
  float4* op = reinterpret_cast<float4*>(out + (long long)v * NF);
  if (active) {
    op[0] = make_float4(acc[0], acc[1], acc[2], acc[3]);
    op[1] = make_float4(acc[4], acc[5], acc[6], acc[7]);
    op[2] = make_float4(acc[8], acc[9], acc[10], acc[11]);
    op[3] = make_float4(acc[12], acc[13], acc[14], acc[15]);
  } else {
    const float4 z4 = make_float4(0.f, 0.f, 0.f, 0.f);
    op[0] = z4; op[1] = z4; op[2] = z4; op[3] = z4;
  }
}

extern "C" void kernel_launch(void* const* d_in, const int* in_sizes, int n_in,
                              void* d_out, int out_size, void* d_ws, size_t ws_size,
                              hipStream_t stream) {
  const float* feat  = (const float*)d_in[0];
  const int*   index = (const int*)d_in[1];
  const float* w     = (const float*)d_in[2];
  const float* bias  = (const float*)d_in[3];
  float*       out   = (float*)d_out;

  const int nvox = in_sizes[1];  // 4*96*96*96 = 3,538,944

  if (ws_size < 14 * 64 * 8 * sizeof(short)) {
    // fallback: pure f32 VALU path
    sparse_conv_f32<<<nvox / 256, 256, 0, stream>>>(feat, index, w, bias, out);
    return;
  }

  short* wpack = (short*)d_ws;
  pack_w<<<1, 14 * 64, 0, stream>>>(w, wpack);

  const int tiles = nvox / 16;          // 221184 waves
  const int blocks = tiles / 4;         // 4 waves per block
  conv_mfma<<<blocks, 256, 0, stream>>>(feat, index, bias,
                                        (const short8*)wpack, out);
}

// Round 3
// 139.473 us; speedup vs baseline: 4.1694x; 3.2882x over previous
//
#include <hip/hip_runtime.h>

#define DSZ 96
#define CIN 16
#define NF  16
#define NXT (DSZ / 8)    // 12 x-tiles
#define NYT (DSZ / 8)    // 12 y-tiles
#define NZT (DSZ / 16)   // 6 z-tiles

typedef __attribute__((ext_vector_type(8))) short short8;   // 8 bf16
typedef __attribute__((ext_vector_type(4))) float f32x4;    // MFMA C/D

union I4S8 { int4 i; short8 s; };

// ---------------- prepass: pack w into B-fragment layout (same as R2) ------
// k = ((lane>>4)&1)*8 + j ; tap = 2t + (lane>>5) ; tap 27 -> zeros.
__global__ void pack_w(const float* __restrict__ w, short* __restrict__ wpack) {
  const int t = threadIdx.x >> 6;   // 0..13
  const int l = threadIdx.x & 63;
  const int tap = 2 * t + (l >> 5);
  const int cib = ((l >> 4) & 1) * 8;
  const int f = l & 15;
  short v[8];
#pragma unroll
  for (int j = 0; j < 8; ++j) {
    float x = (tap <= 26) ? w[(tap * 16 + cib + j) * 16 + f] : 0.0f;
    unsigned u = __float_as_uint(x);
    u = (u + 0x7FFFu + ((u >> 16) & 1u)) >> 16;  // RNE to bf16
    v[j] = (short)u;
  }
  short8 s;
#pragma unroll
  for (int j = 0; j < 8; ++j) s[j] = v[j];
  reinterpret_cast<short8*>(wpack)[t * 64 + l] = s;
}

// Swizzled LDS byte address for granule (col, z', h16) — 16B granules,
// XOR bit4 with z' bit2 -> 16-lane z-stride-32B reads hit 8 distinct
// 4-bank clusters (2-way aliasing only, free per m136).
__device__ __forceinline__ int lds_byte(int col, int zp, int h16) {
  int byte = col * 576 + zp * 32 + h16;   // 576 B per column (18 z * 32 B)
  return byte ^ ((zp & 4) << 2);
}

// ---------------- main: LDS-staged MFMA conv ----------------
// Block = 512 threads (8 waves) = 8x8 xy columns x 16 z outputs.
// Stage 10x10x18 halo as bf16 in LDS once; each wave computes 8 column-tiles.
__global__ __launch_bounds__(512, 4) void conv_mfma_lds(
    const float* __restrict__ feat, const int* __restrict__ index,
    const float* __restrict__ bias, const short8* __restrict__ wpack,
    float* __restrict__ out) {
  __shared__ short smem[100 * 18 * 16];   // 57600 B

  const int tid = threadIdx.x;
  const int lane = tid & 63;
  const int wid = tid >> 6;

  // XCD-aware swizzle (grid 3456 % 8 == 0 -> bijective): each XCD gets a
  // contiguous logical chunk so yt-adjacent tiles share halo in its L2.
  const int d = blockIdx.x;
  int L = (d & 7) * (gridDim.x >> 3) + (d >> 3);
  const int yt = L % NYT;  L /= NYT;
  const int zt = L % NZT;  L /= NZT;
  const int xt = L % NXT;
  const int b  = L / NXT;
  const int x0 = xt * 8, y0 = yt * 8, z0 = zt * 16;

  // B fragments resident in registers for the whole kernel (56 VGPRs).
  short8 bw[14];
#pragma unroll
  for (int t = 0; t < 14; ++t) bw[t] = wpack[t * 64 + lane];

  // ---- stage: 100 cols x 18 z-lines, f32 -> bf16 (truncate via v_perm) ----
  for (int it = tid; it < 1800; it += 512) {
    const int col = it / 18;
    const int zp  = it - col * 18;
    const int colx = col / 10;
    const int coly = col - colx * 10;
    const int gx = x0 + colx - 1, gy = y0 + coly - 1, gz = z0 + zp - 1;
    const bool ok = ((unsigned)gx < (unsigned)DSZ) &
                    ((unsigned)gy < (unsigned)DSZ) &
                    ((unsigned)gz < (unsigned)DSZ);
    const long off = ok ? ((long)(((b * DSZ + gx) * DSZ + gy) * DSZ + gz) * CIN) : 0;
    const float4* p = reinterpret_cast<const float4*>(feat + off);
    float4 q0 = p[0], q1 = p[1], q2 = p[2], q3 = p[3];
    // result bytes = {x.b2, x.b3, y.b2, y.b3} -> perm(hi=y, lo=x, 0x07060302)
    unsigned m0 = __builtin_amdgcn_perm(__float_as_uint(q0.y), __float_as_uint(q0.x), 0x07060302u);
    unsigned m1 = __builtin_amdgcn_perm(__float_as_uint(q0.w), __float_as_uint(q0.z), 0x07060302u);
    unsigned m2 = __builtin_amdgcn_perm(__float_as_uint(q1.y), __float_as_uint(q1.x), 0x07060302u);
    unsigned m3 = __builtin_amdgcn_perm(__float_as_uint(q1.w), __float_as_uint(q1.z), 0x07060302u);
    unsigned m4 = __builtin_amdgcn_perm(__float_as_uint(q2.y), __float_as_uint(q2.x), 0x07060302u);
    unsigned m5 = __builtin_amdgcn_perm(__float_as_uint(q2.w), __float_as_uint(q2.z), 0x07060302u);
    unsigned m6 = __builtin_amdgcn_perm(__float_as_uint(q3.y), __float_as_uint(q3.x), 0x07060302u);
    unsigned m7 = __builtin_amdgcn_perm(__float_as_uint(q3.w), __float_as_uint(q3.z), 0x07060302u);
    if (!ok) { m0 = m1 = m2 = m3 = m4 = m5 = m6 = m7 = 0u; }
    *reinterpret_cast<int4*>((char*)smem + lds_byte(col, zp, 0)) =
        make_int4(m0, m1, m2, m3);
    *reinterpret_cast<int4*>((char*)smem + lds_byte(col, zp, 16)) =
        make_int4(m4, m5, m6, m7);
  }
  __syncthreads();

  // ---- compute: wave wid owns row cx=wid, iterates cy=0..7 ----
  const int z   = lane & 15;    // A row (z within tile)
  const int h16 = lane & 16;    // ci half (granule select)
  const int tp  = lane >> 5;    // tap-of-pair
  const int fq  = lane & 15;    // C/D col (filter)
  const int hq  = lane >> 4;    // C/D row group
  const float bf = bias[fq];
  const int cx = wid;

#pragma unroll 1
  for (int cy = 0; cy < 8; ++cy) {
    int cb[9];
#pragma unroll
    for (int dd = 0; dd < 9; ++dd) {
      const int dx = dd / 3, dy = dd - 3 * (dd / 3);
      cb[dd] = ((cx + dx) * 10 + (cy + dy)) * 576;
    }
    f32x4 acc0 = {0.f, 0.f, 0.f, 0.f};
    f32x4 acc1 = {0.f, 0.f, 0.f, 0.f};
#pragma unroll
    for (int t = 0; t < 14; ++t) {
      const int tapA = 2 * t;
      const int tapB = (2 * t + 1 <= 26) ? (2 * t + 1) : 26;  // tap27: B==0
      const int dA = (tapA / 9) * 3 + (tapA / 3) % 3;
      const int dB = (tapB / 9) * 3 + (tapB / 3) % 3;
      const int dzA = tapA % 3, dzB = tapB % 3;
      const int base = tp ? cb[dB] : cb[dA];
      const int zz = z + (tp ? dzB : dzA);
      const int byte = (base + zz * 32 + h16) ^ ((zz & 4) << 2);
      I4S8 u;
      u.i = *reinterpret_cast<const int4*>((const char*)smem + byte);
      if (t & 1)
        acc1 = __builtin_amdgcn_mfma_f32_16x16x32_bf16(u.s, bw[t], acc1, 0, 0, 0);
      else
        acc0 = __builtin_amdgcn_mfma_f32_16x16x32_bf16(u.s, bw[t], acc0, 0, 0, 0);
    }
    // epilogue: +bias, mask, store
    const int gx = x0 + cx, gy = y0 + cy;
    const int vbase = ((b * DSZ + gx) * DSZ + gy) * DSZ + z0;
    const int4 iv = *reinterpret_cast<const int4*>(index + vbase + hq * 4);
    const int ir0 = iv.x, ir1 = iv.y, ir2 = iv.z, ir3 = iv.w;
    float* op = out + (long)(vbase + hq * 4) * NF + fq;
    op[0 * NF] = ir0 ? (acc0[0] + acc1[0] + bf) : 0.0f;
    op[1 * NF] = ir1 ? (acc0[1] + acc1[1] + bf) : 0.0f;
    op[2 * NF] = ir2 ? (acc0[2] + acc1[2] + bf) : 0.0f;
    op[3 * NF] = ir3 ? (acc0[3] + acc1[3] + bf) : 0.0f;
  }
}

// ---------------- fallback (tiny ws): round-1 f32 kernel ----------------
__global__ __launch_bounds__(256) void sparse_conv_f32(
    const float* __restrict__ feat, const int* __restrict__ index,
    const float* __restrict__ w, const float* __restrict__ bias,
    float* __restrict__ out) {
  const int v = blockIdx.x * 256 + threadIdx.x;
  const int z = v % DSZ;
  int t = v / DSZ;
  const int y = t % DSZ; t /= DSZ;
  const int x = t % DSZ;
  const int bb = t / DSZ;
  float acc[NF];
#pragma unroll
  for (int f = 0; f < NF; ++f) acc[f] = bias[f];
  const bool active = (index[v] != 0);
#pragma unroll 1
  for (int kx = -1; kx <= 1; ++kx) {
    const int xx = x + kx;
    const bool okx = ((unsigned)xx < (unsigned)DSZ);
#pragma unroll 1
    for (int ky = -1; ky <= 1; ++ky) {
      const int yy = y + ky;
      const bool oky = okx && ((unsigned)yy < (unsigned)DSZ);
#pragma unroll 1
      for (int kz = -1; kz <= 1; ++kz) {
        const int zz = z + kz;
        const bool ok = oky && ((unsigned)zz < (unsigned)DSZ);
        const long long off = ((((long long)bb * DSZ + xx) * DSZ + yy) * DSZ + zz) * CIN;
        float4 q0, q1, q2, q3;
        if (ok) {
          const float4* fp = reinterpret_cast<const float4*>(feat + off);
          q0 = fp[0]; q1 = fp[1]; q2 = fp[2]; q3 = fp[3];
        } else {
          q0 = q1 = q2 = q3 = make_float4(0.f, 0.f, 0.f, 0.f);
        }
        const float fv[CIN] = {q0.x, q0.y, q0.z, q0.w, q1.x, q1.y, q1.z, q1.w,
                               q2.x, q2.y, q2.z, q2.w, q3.x, q3.y, q3.z, q3.w};
        const float* wr = w + ((((kx + 1) * 3 + (ky + 1)) * 3 + (kz + 1)) * CIN) * NF;
#pragma unroll
        for (int ci = 0; ci < CIN; ++ci) {
          const float fvv = fv[ci];
#pragma unroll
          for (int f = 0; f < NF; ++f) acc[f] = fmaf(fvv, wr[ci * NF + f], acc[f]);
        }
      }
    }
  }
  float4* op = reinterpret_cast<float4*>(out + (long long)v * NF);
  if (active) {
    op[0] = make_float4(acc[0], acc[1], acc[2], acc[3]);
    op[1] = make_float4(acc[4], acc[5], acc[6], acc[7]);
    op[2] = make_float4(acc[8], acc[9], acc[10], acc[11]);
    op[3] = make_float4(acc[12], acc[13], acc[14], acc[15]);
  } else {
    const float4 z4 = make_float4(0.f, 0.f, 0.f, 0.f);
    op[0] = z4; op[1] = z4; op[2] = z4; op[3] = z4;
  }
}

extern "C" void kernel_launch(void* const* d_in, const int* in_sizes, int n_in,
                              void* d_out, int out_size, void* d_ws, size_t ws_size,
                              hipStream_t stream) {
  const float* feat  = (const float*)d_in[0];
  const int*   index = (const int*)d_in[1];
  const float* w     = (const float*)d_in[2];
  const float* bias  = (const float*)d_in[3];
  float*       out   = (float*)d_out;

  const int nvox = in_sizes[1];  // 4*96*96*96

  if (ws_size < 14 * 64 * 8 * sizeof(short)) {
    sparse_conv_f32<<<nvox / 256, 256, 0, stream>>>(feat, index, w, bias, out);
    return;
  }

  short* wpack = (short*)d_ws;
  pack_w<<<1, 14 * 64, 0, stream>>>(w, wpack);

  const int blocks = 4 * NXT * NYT * NZT;  // 3456
  conv_mfma_lds<<<blocks, 512, 0, stream>>>(feat, index, bias,
                                            (const short8*)wpack, out);
}